// Round 12
// baseline (359.848 us; speedup 1.0000x reference)
//
#include <hip/hip_runtime.h>

#define CH 128          // C_IN == C_OUT == 128
#define SCAN_CHUNK 256
#define SUMS_BLOCK 512
#define CHUNK_E 8192    // records per pass-A chunk
#define BUCKET_BITS 10  // 1024 keys per bucket
#define BKEYS (1 << BUCKET_BITS)
#define NBMAX 512       // max buckets (LDS arrays padded to this)

__device__ inline ushort f2bf(float f) {          // RNE f32 -> bf16
    unsigned b = __float_as_uint(f);
    return (ushort)((b + 0x7FFF + ((b >> 16) & 1)) >> 16);
}
__device__ inline float bf2f(ushort u) {
    return __uint_as_float((unsigned)u << 16);
}

// ---------- generic scan pieces (bucket-major chunk histogram) ----------
__global__ void scan_chunks_kernel(const int* __restrict__ counts, int len,
                                   int* __restrict__ out,
                                   int* __restrict__ chunk_sums) {
    __shared__ int tmp[SCAN_CHUNK];
    int tid = threadIdx.x;
    int i = blockIdx.x * SCAN_CHUNK + tid;
    int v = (i < len) ? counts[i] : 0;
    tmp[tid] = v;
    __syncthreads();
    for (int off = 1; off < SCAN_CHUNK; off <<= 1) {
        int y = (tid >= off) ? tmp[tid - off] : 0;
        __syncthreads();
        tmp[tid] += y;
        __syncthreads();
    }
    if (i < len) out[i] = tmp[tid] - v;            // exclusive
    if (tid == SCAN_CHUNK - 1) chunk_sums[blockIdx.x] = tmp[tid];
}

__global__ void scan_sums_kernel(int* __restrict__ chunk_sums, int nchunks) {
    __shared__ int tmp[SUMS_BLOCK];
    __shared__ int carry_s;
    int tid = threadIdx.x;
    if (tid == 0) carry_s = 0;
    __syncthreads();
    for (int base = 0; base < nchunks; base += SUMS_BLOCK) {
        int i = base + tid;
        int v = (i < nchunks) ? chunk_sums[i] : 0;
        tmp[tid] = v;
        __syncthreads();
        for (int off = 1; off < SUMS_BLOCK; off <<= 1) {
            int y = (tid >= off) ? tmp[tid - off] : 0;
            __syncthreads();
            tmp[tid] += y;
            __syncthreads();
        }
        int c = carry_s;
        if (i < nchunks) chunk_sums[i] = tmp[tid] - v + c;   // exclusive
        int total = tmp[SUMS_BLOCK - 1];
        __syncthreads();
        if (tid == 0) carry_s = c + total;
        __syncthreads();
    }
}

__global__ void add_offsets_plain(int* __restrict__ data, int len,
                                  const int* __restrict__ chunk_sums) {
    int i = blockIdx.x * blockDim.x + threadIdx.x;
    if (i < len) data[i] += chunk_sums[i / SCAN_CHUNK];
}

// ---------- W -> bf16 conversion ----------
__global__ void conv_w_kernel(const float* __restrict__ W,
                              ushort* __restrict__ Wb) {
    int i = blockIdx.x * blockDim.x + threadIdx.x;
    if (i < CH * CH) Wb[i] = f2bf(W[i]);
}

// ---------- radix pass A: per-chunk LDS bucket histogram ----------
// Triple key space: Phi_inv i -> idxA[i]; Phi -> n+idxB[e]; F -> 2n+idxC[e].
__global__ __launch_bounds__(256) void passA_hist(const int* __restrict__ idxA,
                                                  const int* __restrict__ idxB,
                                                  const int* __restrict__ idxC,
                                                  int nnz, int n, int nb, int nchA,
                                                  int* __restrict__ histA) {
    __shared__ int h[NBMAX];
    int t = threadIdx.x;
    for (int s = t; s < nb; s += 256) h[s] = 0;
    __syncthreads();
    int base = blockIdx.x * CHUNK_E;
    int end = min(base + CHUNK_E, 3 * nnz);
    for (int i = base + t; i < end; i += 256) {
        int key;
        if (i < nnz)            key = idxA[i];
        else if (i < 2 * nnz)   key = n + idxB[i - nnz];
        else                    key = 2 * n + idxC[i - 2 * nnz];
        atomicAdd(&h[key >> BUCKET_BITS], 1);
    }
    __syncthreads();
    for (int s = t; s < nb; s += 256)
        histA[(size_t)s * nchA + blockIdx.x] = h[s];   // bucket-major
}

// ---------- radix pass A scatter v2: LDS-staged, coalesced flush ----------
// Chunk's records are counting-sorted by bucket in a 64 KB LDS staging
// buffer, then flushed per-bucket with consecutive lanes -> consecutive
// global addresses (waves touch ~4 lines per store instead of 64).
// recsTmp record (8 B): x = c | (key&1023)<<17  (c < 2^17), y = f32 val bits.
__global__ __launch_bounds__(256) void passA_scatter(const int* __restrict__ idxA,
                                                     const float* __restrict__ valA,
                                                     const int* __restrict__ idxB,
                                                     const float* __restrict__ valB,
                                                     const int* __restrict__ idxC,
                                                     const float* __restrict__ valC,
                                                     const float* __restrict__ theta,
                                                     int nnz, int n, int nb, int nchA,
                                                     const int* __restrict__ offsetA,
                                                     int2* __restrict__ recsTmp) {
    __shared__ int2 stag[CHUNK_E];      // 64 KB
    __shared__ int hist[NBMAX];         // 2 KB
    __shared__ int sc[NBMAX];           // 2 KB (inclusive scan)
    __shared__ int cur[NBMAX];          // 2 KB (scatter cursors)
    int t = threadIdx.x;
    hist[t] = 0; hist[t + 256] = 0;
    __syncthreads();

    int base = blockIdx.x * CHUNK_E;
    int end = min(base + CHUNK_E, 3 * nnz);

    // phase 1: bucket histogram
    for (int i = base + t; i < end; i += 256) {
        int key;
        if (i < nnz)            key = idxA[i];
        else if (i < 2 * nnz)   key = n + idxB[i - nnz];
        else                    key = 2 * n + idxC[i - 2 * nnz];
        atomicAdd(&hist[key >> BUCKET_BITS], 1);
    }
    __syncthreads();

    // phase 2: inclusive scan over 512 slots (2 per thread, Hillis-Steele)
    sc[t] = hist[t]; sc[t + 256] = hist[t + 256];
    __syncthreads();
    for (int off = 1; off < NBMAX; off <<= 1) {
        int a = (t >= off) ? sc[t - off] : 0;
        int b2 = (t + 256 >= off) ? sc[t + 256 - off] : 0;
        __syncthreads();
        sc[t] += a; sc[t + 256] += b2;
        __syncthreads();
    }
    cur[t] = sc[t] - hist[t];
    cur[t + 256] = sc[t + 256] - hist[t + 256];
    __syncthreads();

    // phase 3: scatter records into LDS staging (keys/vals recomputed; L2-hot)
    for (int i = base + t; i < end; i += 256) {
        int key, c;
        float v;
        if (i < nnz) {
            key = idxA[i];
            c = idxA[nnz + i];
            v = valA[i];
        } else if (i < 2 * nnz) {
            int e = i - nnz;
            key = n + idxB[e];
            c = idxB[nnz + e];
            v = valB[e] * theta[c];
        } else {
            int e = i - 2 * nnz;
            key = 2 * n + idxC[e];
            c = idxC[nnz + e];            // F col < 128
            v = valC[e];
        }
        int pos = atomicAdd(&cur[key >> BUCKET_BITS], 1);
        stag[pos] = make_int2(c | ((key & (BKEYS - 1)) << 17),
                              __float_as_int(v));
    }
    __syncthreads();

    // phase 4: coalesced flush, one wave per bucket (round-robin)
    int wave = t >> 6, lane = t & 63;
    for (int b = wave; b < nb; b += 4) {
        int le = sc[b];                 // inclusive end
        int ls = le - hist[b];          // start
        if (ls == le) continue;
        int g = offsetA[(size_t)b * nchA + blockIdx.x];
        for (int k = ls + lane; k < le; k += 64)
            recsTmp[(size_t)g + (k - ls)] = stag[k];
    }
}

// ---------- radix pass B: key-sort within bucket + CSR finalize ----------
// Emits 4 B packed records: rec = (c << 15) | (bf16(v) & 0x7FFF).
// Valid because ALL sparse values here are positive (sign bit always 0).
__global__ __launch_bounds__(1024) void passB_kernel(const int2* __restrict__ recsTmp,
                                                     const int* __restrict__ offsetA,
                                                     int nchA, int nb, int total, int n3,
                                                     int* __restrict__ start_g,
                                                     int* __restrict__ counts_g,
                                                     unsigned* __restrict__ recs) {
    __shared__ int hist[BKEYS];
    __shared__ int scan[BKEYS];
    int b = blockIdx.x;
    int t = threadIdx.x;
    int bs = offsetA[(size_t)b * nchA];
    int be = (b + 1 < nb) ? offsetA[(size_t)(b + 1) * nchA] : total;
    hist[t] = 0;
    __syncthreads();
    for (int i = bs + t; i < be; i += 1024)
        atomicAdd(&hist[(recsTmp[i].x >> 17) & (BKEYS - 1)], 1);
    __syncthreads();
    int v = hist[t];
    scan[t] = v;
    __syncthreads();
    for (int off = 1; off < BKEYS; off <<= 1) {
        int y = (t >= off) ? scan[t - off] : 0;
        __syncthreads();
        scan[t] += y;
        __syncthreads();
    }
    int excl = scan[t] - v;
    int key = (b << BUCKET_BITS) + t;
    if (key < n3) {
        start_g[key] = bs + excl;
        counts_g[key] = v;
    }
    hist[t] = excl;                      // reuse as cursor
    __syncthreads();
    for (int i = bs + t; i < be; i += 1024) {
        int2 r = recsTmp[i];
        int k = (r.x >> 17) & (BKEYS - 1);
        int pos = atomicAdd(&hist[k], 1);
        unsigned c = (unsigned)(r.x & 0x1FFFF);
        unsigned bv = (unsigned)f2bf(__int_as_float(r.y)) & 0x7FFFu;
        recs[bs + pos] = (c << 15) | bv;
    }
}

// ---------- Pull SpMM (bf16 dense operand, 4 B records) ------------------
__global__ __launch_bounds__(256) void pull_spmm_bf16(
        const unsigned* __restrict__ recs,
        const int* __restrict__ start,
        const int* __restrict__ counts,
        const ushort* __restrict__ dense,   // bf16 rows of 128
        ushort* __restrict__ outb,          // bf16 out (or null)
        float* __restrict__ outf,           // f32 out (or null)
        int n, int do_relu) {
    int wave = threadIdx.x >> 6;
    int lane = threadIdx.x & 63;
    int row = blockIdx.x * 4 + wave;
    if (row >= n) return;
    int s = start[row];
    int cnt = counts[row];
    const ushort2* dp = reinterpret_cast<const ushort2*>(dense);
    float ax = 0.0f, ay = 0.0f;
    int j = 0;
    for (; j + 4 <= cnt; j += 4) {
        unsigned r0 = recs[s + j + 0];
        unsigned r1 = recs[s + j + 1];
        unsigned r2 = recs[s + j + 2];
        unsigned r3 = recs[s + j + 3];
        ushort2 d0 = dp[(size_t)(r0 >> 15) * 64 + lane];
        ushort2 d1 = dp[(size_t)(r1 >> 15) * 64 + lane];
        ushort2 d2 = dp[(size_t)(r2 >> 15) * 64 + lane];
        ushort2 d3 = dp[(size_t)(r3 >> 15) * 64 + lane];
        float v0 = __uint_as_float((r0 & 0x7FFFu) << 16);
        float v1 = __uint_as_float((r1 & 0x7FFFu) << 16);
        float v2 = __uint_as_float((r2 & 0x7FFFu) << 16);
        float v3 = __uint_as_float((r3 & 0x7FFFu) << 16);
        ax = fmaf(v0, bf2f(d0.x), ax); ay = fmaf(v0, bf2f(d0.y), ay);
        ax = fmaf(v1, bf2f(d1.x), ax); ay = fmaf(v1, bf2f(d1.y), ay);
        ax = fmaf(v2, bf2f(d2.x), ax); ay = fmaf(v2, bf2f(d2.y), ay);
        ax = fmaf(v3, bf2f(d3.x), ax); ay = fmaf(v3, bf2f(d3.y), ay);
    }
    for (; j < cnt; ++j) {
        unsigned r0 = recs[s + j];
        ushort2 d0 = dp[(size_t)(r0 >> 15) * 64 + lane];
        float v0 = __uint_as_float((r0 & 0x7FFFu) << 16);
        ax = fmaf(v0, bf2f(d0.x), ax); ay = fmaf(v0, bf2f(d0.y), ay);
    }
    if (do_relu) { ax = fmaxf(ax, 0.0f); ay = fmaxf(ay, 0.0f); }
    if (outb) {
        ushort2 o = {f2bf(ax), f2bf(ay)};
        reinterpret_cast<ushort2*>(outb)[(size_t)row * 64 + lane] = o;
    } else {
        float2 o = {ax, ay};
        *reinterpret_cast<float2*>(&outf[(size_t)row * CH + lane * 2]) = o;
    }
}

// ---------- host-side orchestration ----------

extern "C" void kernel_launch(void* const* d_in, const int* in_sizes, int n_in,
                              void* d_out, int out_size, void* d_ws, size_t ws_size,
                              hipStream_t stream) {
    const int*   phi_idx  = (const int*)d_in[0];
    const float* phi_val  = (const float*)d_in[1];
    const int*   phii_idx = (const int*)d_in[2];
    const float* phii_val = (const float*)d_in[3];
    const int*   f_idx    = (const int*)d_in[4];
    const float* f_val    = (const float*)d_in[5];
    const float* W        = (const float*)d_in[6];
    const float* theta    = (const float*)d_in[7];

    const int nnz = in_sizes[1];            // 1,600,000
    const int n   = in_sizes[7];            // 100,000
    const int n3  = 3 * n;                  // triple key space
    const int total = 3 * nnz;              // 4.8M records

    const int nb   = (n3 + BKEYS - 1) >> BUCKET_BITS;               // 293 (<=512)
    const int nchA = (total + CHUNK_E - 1) / CHUNK_E;               // 586
    const int lenA = nb * nchA;

    float* out = (float*)d_out;

    // workspace (~80 MB). The 51.2 MB "dense region" holds recsTmp (38.4 MB)
    // during the build; after passB it is reused as filtered_bf16 [0,25.6) and
    // z_bf16 [25.6,51.2).
    char* ws = (char*)d_ws;
    char*  dense_region = ws;
    int2*  recsTmp  = (int2*)dense_region;                 // 38.4 MB (build only)
    ushort* filt_b  = (ushort*)dense_region;               // 25.6 MB
    ushort* z_b     = (ushort*)(dense_region + (size_t)n * CH * sizeof(ushort));
    ws += (size_t)n * CH * sizeof(float);                  // 51.2 MB region
    unsigned* recs  = (unsigned*)ws;        ws += (size_t)total * sizeof(unsigned);
    int* counts     = (int*)ws;             ws += (size_t)n3 * sizeof(int);
    int* start      = (int*)ws;             ws += (size_t)n3 * sizeof(int);
    int* histA      = (int*)ws;             ws += (size_t)lenA * sizeof(int);
    int* offsetA    = (int*)ws;             ws += (size_t)lenA * sizeof(int);
    int* chunk_sums2= (int*)ws;             ws += 8192;
    ushort* w_b     = (ushort*)ws;          ws += CH * CH * sizeof(ushort);

    const int nchunksA   = (lenA + SCAN_CHUNK - 1) / SCAN_CHUNK;
    const int row_blocks = (n + 3) / 4;

    // --- W -> bf16 (independent; overlaps build) ---
    conv_w_kernel<<<(CH * CH + 255) / 256, 256, 0, stream>>>(W, w_b);

    // --- radix CSR build: all three sparse matrices in one key space ---
    passA_hist<<<nchA, 256, 0, stream>>>(phii_idx, phi_idx, f_idx,
                                         nnz, n, nb, nchA, histA);
    scan_chunks_kernel<<<nchunksA, SCAN_CHUNK, 0, stream>>>(histA, lenA, offsetA, chunk_sums2);
    scan_sums_kernel<<<1, SUMS_BLOCK, 0, stream>>>(chunk_sums2, nchunksA);
    add_offsets_plain<<<(lenA + 255) / 256, 256, 0, stream>>>(offsetA, lenA, chunk_sums2);
    passA_scatter<<<nchA, 256, 0, stream>>>(phii_idx, phii_val, phi_idx, phi_val,
                                            f_idx, f_val, theta,
                                            nnz, n, nb, nchA, offsetA, recsTmp);
    passB_kernel<<<nb, 1024, 0, stream>>>(recsTmp, offsetA, nchA, nb, total, n3,
                                          start, counts, recs);

    // 1) filtered = F @ W       (keys [2n,3n); W bf16 L1-resident; bf16 out)
    pull_spmm_bf16<<<row_blocks, 256, 0, stream>>>(
        recs, start + 2 * n, counts + 2 * n, w_b, filt_b, nullptr, n, 0);

    // 2) z = Phi_inv @ filtered (keys [0,n); bf16 in/out)
    pull_spmm_bf16<<<row_blocks, 256, 0, stream>>>(
        recs, start, counts, filt_b, z_b, nullptr, n, 0);

    // 3) out = relu(Phi @ (theta .* z))  (keys [n,2n); theta pre-folded; f32 out)
    pull_spmm_bf16<<<row_blocks, 256, 0, stream>>>(
        recs, start + n, counts + n, z_b, nullptr, out, n, 1);
}

// Round 13
// 347.294 us; speedup vs baseline: 1.0361x; 1.0361x over previous
//
#include <hip/hip_runtime.h>

#define CH 128          // C_IN == C_OUT == 128
#define SUMS_BLOCK 512
#define CHUNK_E 4096    // records per chunk = private 32 KB recsTmp window
#define BUCKET_BITS 10  // 1024 keys per bucket
#define BKEYS (1 << BUCKET_BITS)
#define NBMAX 512       // max buckets (LDS arrays padded to this)

__device__ inline ushort f2bf(float f) {          // RNE f32 -> bf16
    unsigned b = __float_as_uint(f);
    return (ushort)((b + 0x7FFF + ((b >> 16) & 1)) >> 16);
}
__device__ inline float bf2f(ushort u) {
    return __uint_as_float((unsigned)u << 16);
}

// ---------- W -> bf16 conversion ----------
__global__ void conv_w_kernel(const float* __restrict__ W,
                              ushort* __restrict__ Wb) {
    int i = blockIdx.x * blockDim.x + threadIdx.x;
    if (i < CH * CH) Wb[i] = f2bf(W[i]);
}

// ---------- pass A: per-chunk bucket sort into PRIVATE global window -----
// Triple key space: Phi_inv i -> idxA[i]; Phi -> n+idxB[e]; F -> 2n+idxC[e].
// Block ch owns recsTmp[ch*CHUNK_E ...): records bucket-sorted within the
// chunk. locA (chunk-major, nb+1 per chunk) holds the local exclusive
// bucket starts + sentinel (=chunk size). No global scan needed.
// recsTmp record (8 B): x = c | (key&1023)<<17  (c < 2^17), y = f32 val bits.
__global__ __launch_bounds__(256) void passA_sort(const int* __restrict__ idxA,
                                                  const float* __restrict__ valA,
                                                  const int* __restrict__ idxB,
                                                  const float* __restrict__ valB,
                                                  const int* __restrict__ idxC,
                                                  const float* __restrict__ valC,
                                                  const float* __restrict__ theta,
                                                  int nnz, int n, int nb,
                                                  int* __restrict__ locA,
                                                  int2* __restrict__ recsTmp) {
    __shared__ int hist[NBMAX];
    __shared__ int sc[NBMAX];
    __shared__ int cur[NBMAX];
    int t = threadIdx.x;
    hist[t] = 0; hist[t + 256] = 0;
    __syncthreads();

    int base = blockIdx.x * CHUNK_E;
    int end = min(base + CHUNK_E, 3 * nnz);
    int csize = end - base;

    // phase 1: bucket histogram (keys only)
    for (int i = base + t; i < end; i += 256) {
        int key;
        if (i < nnz)            key = idxA[i];
        else if (i < 2 * nnz)   key = n + idxB[i - nnz];
        else                    key = 2 * n + idxC[i - 2 * nnz];
        atomicAdd(&hist[key >> BUCKET_BITS], 1);
    }
    __syncthreads();

    // phase 2: inclusive scan over 512 slots (2/thread, Hillis-Steele)
    sc[t] = hist[t]; sc[t + 256] = hist[t + 256];
    __syncthreads();
    for (int off = 1; off < NBMAX; off <<= 1) {
        int a = (t >= off) ? sc[t - off] : 0;
        int b2 = (t + 256 >= off) ? sc[t + 256 - off] : 0;
        __syncthreads();
        sc[t] += a; sc[t + 256] += b2;
        __syncthreads();
    }
    cur[t] = sc[t] - hist[t];
    cur[t + 256] = sc[t + 256] - hist[t + 256];
    __syncthreads();

    // metadata: contiguous chunk-major write (local exclusive starts + sentinel)
    for (int b = t; b <= nb; b += 256)
        locA[(size_t)blockIdx.x * (nb + 1) + b] = (b < nb) ? (sc[b] - hist[b]) : csize;

    // phase 3: re-read, scatter into private 32 KB window (L2-resident, 1 writer)
    for (int i = base + t; i < end; i += 256) {
        int key, c;
        float v;
        if (i < nnz) {
            key = idxA[i];
            c = idxA[nnz + i];
            v = valA[i];
        } else if (i < 2 * nnz) {
            int e = i - nnz;
            key = n + idxB[e];
            c = idxB[nnz + e];
            v = valB[e] * theta[c];
        } else {
            int e = i - 2 * nnz;
            key = 2 * n + idxC[e];
            c = idxC[nnz + e];            // F col < 128
            v = valC[e];
        }
        int pos = atomicAdd(&cur[key >> BUCKET_BITS], 1);
        recsTmp[(size_t)base + pos] = make_int2(c | ((key & (BKEYS - 1)) << 17),
                                                __float_as_int(v));
    }
}

// ---------- bucket totals: tot[b] = sum over chunks of segment length -----
__global__ __launch_bounds__(256) void bucket_totals(const int* __restrict__ locA,
                                                     int nchA, int nb,
                                                     int* __restrict__ tot) {
    __shared__ int red[256];
    int b = blockIdx.x;
    int t = threadIdx.x;
    int s = 0;
    for (int ch = t; ch < nchA; ch += 256) {
        const int* lc = &locA[(size_t)ch * (nb + 1)];
        s += lc[b + 1] - lc[b];
    }
    red[t] = s;
    __syncthreads();
    for (int off = 128; off > 0; off >>= 1) {
        if (t < off) red[t] += red[t + off];
        __syncthreads();
    }
    if (t == 0) tot[b] = red[0];
}

// exclusive scan in place over tot[0..len) (len <= SUMS_BLOCK loop-handled)
__global__ void scan_sums_kernel(int* __restrict__ chunk_sums, int nchunks) {
    __shared__ int tmp[SUMS_BLOCK];
    __shared__ int carry_s;
    int tid = threadIdx.x;
    if (tid == 0) carry_s = 0;
    __syncthreads();
    for (int base = 0; base < nchunks; base += SUMS_BLOCK) {
        int i = base + tid;
        int v = (i < nchunks) ? chunk_sums[i] : 0;
        tmp[tid] = v;
        __syncthreads();
        for (int off = 1; off < SUMS_BLOCK; off <<= 1) {
            int y = (tid >= off) ? tmp[tid - off] : 0;
            __syncthreads();
            tmp[tid] += y;
            __syncthreads();
        }
        int c = carry_s;
        if (i < nchunks) chunk_sums[i] = tmp[tid] - v + c;   // exclusive
        int total = tmp[SUMS_BLOCK - 1];
        __syncthreads();
        if (tid == 0) carry_s = c + total;
        __syncthreads();
    }
}

// ---------- pass B: gather bucket segments, key-sort, CSR finalize --------
// One block per bucket. Reads bucket b's segment from every chunk's private
// window (short sequential runs), LDS key-histogram -> scan -> coalesced
// start/counts writes -> scatter into final recs[bs..) (4 B packed).
// rec = (c << 15) | (bf16(v) & 0x7FFF)  -- all values positive.
__global__ __launch_bounds__(1024) void passB_kernel(const int2* __restrict__ recsTmp,
                                                     const int* __restrict__ locA,
                                                     const int* __restrict__ bsArr,
                                                     int nchA, int nb, int n3,
                                                     int* __restrict__ start_g,
                                                     int* __restrict__ counts_g,
                                                     unsigned* __restrict__ recs) {
    __shared__ int hist[BKEYS];
    __shared__ int scan[BKEYS];
    int b = blockIdx.x;
    int t = threadIdx.x;
    int wave = t >> 6, lane = t & 63;
    int bs = bsArr[b];
    hist[t] = 0;
    __syncthreads();

    // phase 1: key histogram over all segments of this bucket
    for (int ch = wave; ch < nchA; ch += 16) {
        const int* lc = &locA[(size_t)ch * (nb + 1)];
        int ls = lc[b], le = lc[b + 1];
        int cb = ch * CHUNK_E;
        for (int k = ls + lane; k < le; k += 64)
            atomicAdd(&hist[(recsTmp[(size_t)cb + k].x >> 17) & (BKEYS - 1)], 1);
    }
    __syncthreads();

    // phase 2: scan 1024 keys
    int v = hist[t];
    scan[t] = v;
    __syncthreads();
    for (int off = 1; off < BKEYS; off <<= 1) {
        int y = (t >= off) ? scan[t - off] : 0;
        __syncthreads();
        scan[t] += y;
        __syncthreads();
    }
    int excl = scan[t] - v;
    int key = (b << BUCKET_BITS) + t;
    if (key < n3) {
        start_g[key] = bs + excl;
        counts_g[key] = v;
    }
    hist[t] = excl;                      // reuse as cursor
    __syncthreads();

    // phase 3: re-read segments, write final packed records
    for (int ch = wave; ch < nchA; ch += 16) {
        const int* lc = &locA[(size_t)ch * (nb + 1)];
        int ls = lc[b], le = lc[b + 1];
        int cb = ch * CHUNK_E;
        for (int k = ls + lane; k < le; k += 64) {
            int2 r = recsTmp[(size_t)cb + k];
            int kk = (r.x >> 17) & (BKEYS - 1);
            int pos = atomicAdd(&hist[kk], 1);
            unsigned c = (unsigned)(r.x & 0x1FFFF);
            unsigned bv = (unsigned)f2bf(__int_as_float(r.y)) & 0x7FFFu;
            recs[(size_t)bs + pos] = (c << 15) | bv;
        }
    }
}

// ---------- Pull SpMM (bf16 dense operand, 4 B records) ------------------
__global__ __launch_bounds__(256) void pull_spmm_bf16(
        const unsigned* __restrict__ recs,
        const int* __restrict__ start,
        const int* __restrict__ counts,
        const ushort* __restrict__ dense,   // bf16 rows of 128
        ushort* __restrict__ outb,          // bf16 out (or null)
        float* __restrict__ outf,           // f32 out (or null)
        int n, int do_relu) {
    int wave = threadIdx.x >> 6;
    int lane = threadIdx.x & 63;
    int row = blockIdx.x * 4 + wave;
    if (row >= n) return;
    int s = start[row];
    int cnt = counts[row];
    const ushort2* dp = reinterpret_cast<const ushort2*>(dense);
    float ax = 0.0f, ay = 0.0f;
    int j = 0;
    for (; j + 4 <= cnt; j += 4) {
        unsigned r0 = recs[s + j + 0];
        unsigned r1 = recs[s + j + 1];
        unsigned r2 = recs[s + j + 2];
        unsigned r3 = recs[s + j + 3];
        ushort2 d0 = dp[(size_t)(r0 >> 15) * 64 + lane];
        ushort2 d1 = dp[(size_t)(r1 >> 15) * 64 + lane];
        ushort2 d2 = dp[(size_t)(r2 >> 15) * 64 + lane];
        ushort2 d3 = dp[(size_t)(r3 >> 15) * 64 + lane];
        float v0 = __uint_as_float((r0 & 0x7FFFu) << 16);
        float v1 = __uint_as_float((r1 & 0x7FFFu) << 16);
        float v2 = __uint_as_float((r2 & 0x7FFFu) << 16);
        float v3 = __uint_as_float((r3 & 0x7FFFu) << 16);
        ax = fmaf(v0, bf2f(d0.x), ax); ay = fmaf(v0, bf2f(d0.y), ay);
        ax = fmaf(v1, bf2f(d1.x), ax); ay = fmaf(v1, bf2f(d1.y), ay);
        ax = fmaf(v2, bf2f(d2.x), ax); ay = fmaf(v2, bf2f(d2.y), ay);
        ax = fmaf(v3, bf2f(d3.x), ax); ay = fmaf(v3, bf2f(d3.y), ay);
    }
    for (; j < cnt; ++j) {
        unsigned r0 = recs[s + j];
        ushort2 d0 = dp[(size_t)(r0 >> 15) * 64 + lane];
        float v0 = __uint_as_float((r0 & 0x7FFFu) << 16);
        ax = fmaf(v0, bf2f(d0.x), ax); ay = fmaf(v0, bf2f(d0.y), ay);
    }
    if (do_relu) { ax = fmaxf(ax, 0.0f); ay = fmaxf(ay, 0.0f); }
    if (outb) {
        ushort2 o = {f2bf(ax), f2bf(ay)};
        reinterpret_cast<ushort2*>(outb)[(size_t)row * 64 + lane] = o;
    } else {
        float2 o = {ax, ay};
        *reinterpret_cast<float2*>(&outf[(size_t)row * CH + lane * 2]) = o;
    }
}

// ---------- host-side orchestration ----------

extern "C" void kernel_launch(void* const* d_in, const int* in_sizes, int n_in,
                              void* d_out, int out_size, void* d_ws, size_t ws_size,
                              hipStream_t stream) {
    const int*   phi_idx  = (const int*)d_in[0];
    const float* phi_val  = (const float*)d_in[1];
    const int*   phii_idx = (const int*)d_in[2];
    const float* phii_val = (const float*)d_in[3];
    const int*   f_idx    = (const int*)d_in[4];
    const float* f_val    = (const float*)d_in[5];
    const float* W        = (const float*)d_in[6];
    const float* theta    = (const float*)d_in[7];

    const int nnz = in_sizes[1];            // 1,600,000
    const int n   = in_sizes[7];            // 100,000
    const int n3  = 3 * n;                  // triple key space
    const int total = 3 * nnz;              // 4.8M records

    const int nb   = (n3 + BKEYS - 1) >> BUCKET_BITS;               // 293 (<=511)
    const int nchA = (total + CHUNK_E - 1) / CHUNK_E;               // 1172

    float* out = (float*)d_out;

    // workspace (~75 MB). The 51.2 MB "dense region" holds recsTmp (38.4 MB)
    // during the build; after passB it is reused as filtered_bf16 [0,25.6)
    // and z_bf16 [25.6,51.2).
    char* ws = (char*)d_ws;
    char*  dense_region = ws;
    int2*  recsTmp  = (int2*)dense_region;                 // 38.4 MB (build only)
    ushort* filt_b  = (ushort*)dense_region;               // 25.6 MB
    ushort* z_b     = (ushort*)(dense_region + (size_t)n * CH * sizeof(ushort));
    ws += (size_t)n * CH * sizeof(float);                  // 51.2 MB region
    unsigned* recs  = (unsigned*)ws;        ws += (size_t)total * sizeof(unsigned);
    int* counts     = (int*)ws;             ws += (size_t)n3 * sizeof(int);
    int* start      = (int*)ws;             ws += (size_t)n3 * sizeof(int);
    int* locA       = (int*)ws;             ws += (size_t)nchA * (nb + 1) * sizeof(int);
    int* tot        = (int*)ws;             ws += 4096;
    ushort* w_b     = (ushort*)ws;          ws += CH * CH * sizeof(ushort);

    const int row_blocks = (n + 3) / 4;

    // --- W -> bf16 (independent; overlaps build) ---
    conv_w_kernel<<<(CH * CH + 255) / 256, 256, 0, stream>>>(W, w_b);

    // --- radix CSR build: all three sparse matrices in one key space ---
    passA_sort<<<nchA, 256, 0, stream>>>(phii_idx, phii_val, phi_idx, phi_val,
                                         f_idx, f_val, theta,
                                         nnz, n, nb, locA, recsTmp);
    bucket_totals<<<nb, 256, 0, stream>>>(locA, nchA, nb, tot);
    scan_sums_kernel<<<1, SUMS_BLOCK, 0, stream>>>(tot, nb);
    passB_kernel<<<nb, 1024, 0, stream>>>(recsTmp, locA, tot, nchA, nb, n3,
                                          start, counts, recs);

    // 1) filtered = F @ W       (keys [2n,3n); W bf16 L1-resident; bf16 out)
    pull_spmm_bf16<<<row_blocks, 256, 0, stream>>>(
        recs, start + 2 * n, counts + 2 * n, w_b, filt_b, nullptr, n, 0);

    // 2) z = Phi_inv @ filtered (keys [0,n); bf16 in/out)
    pull_spmm_bf16<<<row_blocks, 256, 0, stream>>>(
        recs, start, counts, filt_b, z_b, nullptr, n, 0);

    // 3) out = relu(Phi @ (theta .* z))  (keys [n,2n); theta pre-folded; f32 out)
    pull_spmm_bf16<<<row_blocks, 256, 0, stream>>>(
        recs, start + n, counts + n, z_b, nullptr, out, n, 1);
}

// Round 14
// 282.997 us; speedup vs baseline: 1.2716x; 1.2272x over previous
//
#include <hip/hip_runtime.h>

#define CH 128          // C_IN == C_OUT == 128
#define SUMS_BLOCK 512
#define CHUNK_E 4096    // records per chunk = private 32 KB recsTmp window
#define BUCKET_BITS 10  // 1024 keys per bucket
#define BKEYS (1 << BUCKET_BITS)
#define NBMAX 512       // max buckets (LDS arrays padded to this)
#define STAG_CAP 18432  // passB LDS out-buffer capacity (mean 16384 + 16 sigma)

__device__ inline ushort f2bf(float f) {          // RNE f32 -> bf16
    unsigned b = __float_as_uint(f);
    return (ushort)((b + 0x7FFF + ((b >> 16) & 1)) >> 16);
}
__device__ inline float bf2f(ushort u) {
    return __uint_as_float((unsigned)u << 16);
}

// ---------- W -> bf16 conversion ----------
__global__ void conv_w_kernel(const float* __restrict__ W,
                              ushort* __restrict__ Wb) {
    int i = blockIdx.x * blockDim.x + threadIdx.x;
    if (i < CH * CH) Wb[i] = f2bf(W[i]);
}

// ---------- pass A: per-chunk bucket sort into PRIVATE global window -----
// Triple key space: Phi_inv i -> idxA[i]; Phi -> n+idxB[e]; F -> 2n+idxC[e].
// recsTmp record (8 B): x = c | (key&1023)<<17  (c < 2^17), y = f32 val bits.
__global__ __launch_bounds__(256) void passA_sort(const int* __restrict__ idxA,
                                                  const float* __restrict__ valA,
                                                  const int* __restrict__ idxB,
                                                  const float* __restrict__ valB,
                                                  const int* __restrict__ idxC,
                                                  const float* __restrict__ valC,
                                                  const float* __restrict__ theta,
                                                  int nnz, int n, int nb,
                                                  int* __restrict__ locA,
                                                  int2* __restrict__ recsTmp) {
    __shared__ int hist[NBMAX];
    __shared__ int sc[NBMAX];
    __shared__ int cur[NBMAX];
    int t = threadIdx.x;
    hist[t] = 0; hist[t + 256] = 0;
    __syncthreads();

    int base = blockIdx.x * CHUNK_E;
    int end = min(base + CHUNK_E, 3 * nnz);
    int csize = end - base;

    // phase 1: bucket histogram (keys only)
    for (int i = base + t; i < end; i += 256) {
        int key;
        if (i < nnz)            key = idxA[i];
        else if (i < 2 * nnz)   key = n + idxB[i - nnz];
        else                    key = 2 * n + idxC[i - 2 * nnz];
        atomicAdd(&hist[key >> BUCKET_BITS], 1);
    }
    __syncthreads();

    // phase 2: inclusive scan over 512 slots (2/thread, Hillis-Steele)
    sc[t] = hist[t]; sc[t + 256] = hist[t + 256];
    __syncthreads();
    for (int off = 1; off < NBMAX; off <<= 1) {
        int a = (t >= off) ? sc[t - off] : 0;
        int b2 = (t + 256 >= off) ? sc[t + 256 - off] : 0;
        __syncthreads();
        sc[t] += a; sc[t + 256] += b2;
        __syncthreads();
    }
    cur[t] = sc[t] - hist[t];
    cur[t + 256] = sc[t + 256] - hist[t + 256];
    __syncthreads();

    // metadata: contiguous chunk-major write (local exclusive starts + sentinel)
    for (int b = t; b <= nb; b += 256)
        locA[(size_t)blockIdx.x * (nb + 1) + b] = (b < nb) ? (sc[b] - hist[b]) : csize;

    // phase 3: re-read, scatter into private 32 KB window (L2-resident, 1 writer)
    for (int i = base + t; i < end; i += 256) {
        int key, c;
        float v;
        if (i < nnz) {
            key = idxA[i];
            c = idxA[nnz + i];
            v = valA[i];
        } else if (i < 2 * nnz) {
            int e = i - nnz;
            key = n + idxB[e];
            c = idxB[nnz + e];
            v = valB[e] * theta[c];
        } else {
            int e = i - 2 * nnz;
            key = 2 * n + idxC[e];
            c = idxC[nnz + e];            // F col < 128
            v = valC[e];
        }
        int pos = atomicAdd(&cur[key >> BUCKET_BITS], 1);
        recsTmp[(size_t)base + pos] = make_int2(c | ((key & (BKEYS - 1)) << 17),
                                                __float_as_int(v));
    }
}

// ---------- bucket totals: tot[b] = sum over chunks of segment length -----
__global__ __launch_bounds__(256) void bucket_totals(const int* __restrict__ locA,
                                                     int nchA, int nb,
                                                     int* __restrict__ tot) {
    __shared__ int red[256];
    int b = blockIdx.x;
    int t = threadIdx.x;
    int s = 0;
    for (int ch = t; ch < nchA; ch += 256) {
        const int* lc = &locA[(size_t)ch * (nb + 1)];
        s += lc[b + 1] - lc[b];
    }
    red[t] = s;
    __syncthreads();
    for (int off = 128; off > 0; off >>= 1) {
        if (t < off) red[t] += red[t + off];
        __syncthreads();
    }
    if (t == 0) tot[b] = red[0];
}

// exclusive scan in place over tot[0..len)
__global__ void scan_sums_kernel(int* __restrict__ chunk_sums, int nchunks) {
    __shared__ int tmp[SUMS_BLOCK];
    __shared__ int carry_s;
    int tid = threadIdx.x;
    if (tid == 0) carry_s = 0;
    __syncthreads();
    for (int base = 0; base < nchunks; base += SUMS_BLOCK) {
        int i = base + tid;
        int v = (i < nchunks) ? chunk_sums[i] : 0;
        tmp[tid] = v;
        __syncthreads();
        for (int off = 1; off < SUMS_BLOCK; off <<= 1) {
            int y = (tid >= off) ? tmp[tid - off] : 0;
            __syncthreads();
            tmp[tid] += y;
            __syncthreads();
        }
        int c = carry_s;
        if (i < nchunks) chunk_sums[i] = tmp[tid] - v + c;   // exclusive
        int total = tmp[SUMS_BLOCK - 1];
        __syncthreads();
        if (tid == 0) carry_s = c + total;
        __syncthreads();
    }
}

// ---------- pass B v2: key-sort into LDS out-buffer, linear flush ---------
// One block per bucket. 16-lane chunk groups read segments (4 chunks per
// wave concurrently). Records are packed to 4 B and scattered into an LDS
// out-buffer; the final global write is a linear coalesced burst (full
// lines by construction -> no write amplification, L2-eviction immune).
// rec = (c << 15) | (bf16(v) & 0x7FFF)  -- all values positive.
__global__ __launch_bounds__(1024) void passB_kernel(const int2* __restrict__ recsTmp,
                                                     const int* __restrict__ locA,
                                                     const int* __restrict__ bsArr,
                                                     int nchA, int nb, int n3,
                                                     int* __restrict__ start_g,
                                                     int* __restrict__ counts_g,
                                                     unsigned* __restrict__ recs) {
    __shared__ int hist[BKEYS];          // 4 KB
    __shared__ int scan[BKEYS];          // 4 KB
    __shared__ unsigned outb[STAG_CAP];  // 72 KB
    int b = blockIdx.x;
    int t = threadIdx.x;
    int wave = t >> 6, lane = t & 63;
    int grp = lane >> 4, gl = lane & 15;    // 4 chunk-groups per wave
    int bs = bsArr[b];
    hist[t] = 0;
    __syncthreads();

    // phase 1: key histogram (64 chunks in flight across the block)
    for (int ch = wave * 4 + grp; ch < nchA; ch += 64) {
        const int* lc = &locA[(size_t)ch * (nb + 1)];
        int ls = lc[b], le = lc[b + 1];
        size_t cb = (size_t)ch * CHUNK_E;
        for (int k = ls + gl; k < le; k += 16)
            atomicAdd(&hist[(recsTmp[cb + k].x >> 17) & (BKEYS - 1)], 1);
    }
    __syncthreads();

    // phase 2: scan 1024 keys
    int v = hist[t];
    scan[t] = v;
    __syncthreads();
    for (int off = 1; off < BKEYS; off <<= 1) {
        int y = (t >= off) ? scan[t - off] : 0;
        __syncthreads();
        scan[t] += y;
        __syncthreads();
    }
    int excl = scan[t] - v;
    int key = (b << BUCKET_BITS) + t;
    if (key < n3) {
        start_g[key] = bs + excl;
        counts_g[key] = v;
    }
    int totalB = scan[BKEYS - 1];
    hist[t] = excl;                      // reuse as cursor
    __syncthreads();

    if (totalB <= STAG_CAP) {
        // phase 3: re-read segments, pack, scatter into LDS out-buffer
        for (int ch = wave * 4 + grp; ch < nchA; ch += 64) {
            const int* lc = &locA[(size_t)ch * (nb + 1)];
            int ls = lc[b], le = lc[b + 1];
            size_t cb = (size_t)ch * CHUNK_E;
            for (int k = ls + gl; k < le; k += 16) {
                int2 r = recsTmp[cb + k];
                int kk = (r.x >> 17) & (BKEYS - 1);
                int pos = atomicAdd(&hist[kk], 1);
                unsigned c = (unsigned)(r.x & 0x1FFFF);
                unsigned bv = (unsigned)f2bf(__int_as_float(r.y)) & 0x7FFFu;
                outb[pos] = (c << 15) | bv;
            }
        }
        __syncthreads();
        // phase 4: linear coalesced flush
        for (int k = t; k < totalB; k += 1024)
            recs[(size_t)bs + k] = outb[k];
    } else {
        // fallback (statistically unreachable): direct global scatter
        for (int ch = wave * 4 + grp; ch < nchA; ch += 64) {
            const int* lc = &locA[(size_t)ch * (nb + 1)];
            int ls = lc[b], le = lc[b + 1];
            size_t cb = (size_t)ch * CHUNK_E;
            for (int k = ls + gl; k < le; k += 16) {
                int2 r = recsTmp[cb + k];
                int kk = (r.x >> 17) & (BKEYS - 1);
                int pos = atomicAdd(&hist[kk], 1);
                unsigned c = (unsigned)(r.x & 0x1FFFF);
                unsigned bv = (unsigned)f2bf(__int_as_float(r.y)) & 0x7FFFu;
                recs[(size_t)bs + pos] = (c << 15) | bv;
            }
        }
    }
}

// ---------- Pull SpMM (bf16 dense operand, 4 B records) ------------------
__global__ __launch_bounds__(256) void pull_spmm_bf16(
        const unsigned* __restrict__ recs,
        const int* __restrict__ start,
        const int* __restrict__ counts,
        const ushort* __restrict__ dense,   // bf16 rows of 128
        ushort* __restrict__ outb,          // bf16 out (or null)
        float* __restrict__ outf,           // f32 out (or null)
        int n, int do_relu) {
    int wave = threadIdx.x >> 6;
    int lane = threadIdx.x & 63;
    int row = blockIdx.x * 4 + wave;
    if (row >= n) return;
    int s = start[row];
    int cnt = counts[row];
    const ushort2* dp = reinterpret_cast<const ushort2*>(dense);
    float ax = 0.0f, ay = 0.0f;
    int j = 0;
    for (; j + 4 <= cnt; j += 4) {
        unsigned r0 = recs[s + j + 0];
        unsigned r1 = recs[s + j + 1];
        unsigned r2 = recs[s + j + 2];
        unsigned r3 = recs[s + j + 3];
        ushort2 d0 = dp[(size_t)(r0 >> 15) * 64 + lane];
        ushort2 d1 = dp[(size_t)(r1 >> 15) * 64 + lane];
        ushort2 d2 = dp[(size_t)(r2 >> 15) * 64 + lane];
        ushort2 d3 = dp[(size_t)(r3 >> 15) * 64 + lane];
        float v0 = __uint_as_float((r0 & 0x7FFFu) << 16);
        float v1 = __uint_as_float((r1 & 0x7FFFu) << 16);
        float v2 = __uint_as_float((r2 & 0x7FFFu) << 16);
        float v3 = __uint_as_float((r3 & 0x7FFFu) << 16);
        ax = fmaf(v0, bf2f(d0.x), ax); ay = fmaf(v0, bf2f(d0.y), ay);
        ax = fmaf(v1, bf2f(d1.x), ax); ay = fmaf(v1, bf2f(d1.y), ay);
        ax = fmaf(v2, bf2f(d2.x), ax); ay = fmaf(v2, bf2f(d2.y), ay);
        ax = fmaf(v3, bf2f(d3.x), ax); ay = fmaf(v3, bf2f(d3.y), ay);
    }
    for (; j < cnt; ++j) {
        unsigned r0 = recs[s + j];
        ushort2 d0 = dp[(size_t)(r0 >> 15) * 64 + lane];
        float v0 = __uint_as_float((r0 & 0x7FFFu) << 16);
        ax = fmaf(v0, bf2f(d0.x), ax); ay = fmaf(v0, bf2f(d0.y), ay);
    }
    if (do_relu) { ax = fmaxf(ax, 0.0f); ay = fmaxf(ay, 0.0f); }
    if (outb) {
        ushort2 o = {f2bf(ax), f2bf(ay)};
        reinterpret_cast<ushort2*>(outb)[(size_t)row * 64 + lane] = o;
    } else {
        float2 o = {ax, ay};
        *reinterpret_cast<float2*>(&outf[(size_t)row * CH + lane * 2]) = o;
    }
}

// ---------- host-side orchestration ----------

extern "C" void kernel_launch(void* const* d_in, const int* in_sizes, int n_in,
                              void* d_out, int out_size, void* d_ws, size_t ws_size,
                              hipStream_t stream) {
    const int*   phi_idx  = (const int*)d_in[0];
    const float* phi_val  = (const float*)d_in[1];
    const int*   phii_idx = (const int*)d_in[2];
    const float* phii_val = (const float*)d_in[3];
    const int*   f_idx    = (const int*)d_in[4];
    const float* f_val    = (const float*)d_in[5];
    const float* W        = (const float*)d_in[6];
    const float* theta    = (const float*)d_in[7];

    const int nnz = in_sizes[1];            // 1,600,000
    const int n   = in_sizes[7];            // 100,000
    const int n3  = 3 * n;                  // triple key space
    const int total = 3 * nnz;              // 4.8M records

    const int nb   = (n3 + BKEYS - 1) >> BUCKET_BITS;               // 293 (<=511)
    const int nchA = (total + CHUNK_E - 1) / CHUNK_E;               // 1172

    float* out = (float*)d_out;

    // workspace (~75 MB). The 51.2 MB "dense region" holds recsTmp (38.4 MB)
    // during the build; after passB it is reused as filtered_bf16 [0,25.6)
    // and z_bf16 [25.6,51.2).
    char* ws = (char*)d_ws;
    char*  dense_region = ws;
    int2*  recsTmp  = (int2*)dense_region;                 // 38.4 MB (build only)
    ushort* filt_b  = (ushort*)dense_region;               // 25.6 MB
    ushort* z_b     = (ushort*)(dense_region + (size_t)n * CH * sizeof(ushort));
    ws += (size_t)n * CH * sizeof(float);                  // 51.2 MB region
    unsigned* recs  = (unsigned*)ws;        ws += (size_t)total * sizeof(unsigned);
    int* counts     = (int*)ws;             ws += (size_t)n3 * sizeof(int);
    int* start      = (int*)ws;             ws += (size_t)n3 * sizeof(int);
    int* locA       = (int*)ws;             ws += (size_t)nchA * (nb + 1) * sizeof(int);
    int* tot        = (int*)ws;             ws += 4096;
    ushort* w_b     = (ushort*)ws;          ws += CH * CH * sizeof(ushort);

    const int row_blocks = (n + 3) / 4;

    // --- W -> bf16 (independent; overlaps build) ---
    conv_w_kernel<<<(CH * CH + 255) / 256, 256, 0, stream>>>(W, w_b);

    // --- radix CSR build: all three sparse matrices in one key space ---
    passA_sort<<<nchA, 256, 0, stream>>>(phii_idx, phii_val, phi_idx, phi_val,
                                         f_idx, f_val, theta,
                                         nnz, n, nb, locA, recsTmp);
    bucket_totals<<<nb, 256, 0, stream>>>(locA, nchA, nb, tot);
    scan_sums_kernel<<<1, SUMS_BLOCK, 0, stream>>>(tot, nb);
    passB_kernel<<<nb, 1024, 0, stream>>>(recsTmp, locA, tot, nchA, nb, n3,
                                          start, counts, recs);

    // 1) filtered = F @ W       (keys [2n,3n); W bf16 L1-resident; bf16 out)
    pull_spmm_bf16<<<row_blocks, 256, 0, stream>>>(
        recs, start + 2 * n, counts + 2 * n, w_b, filt_b, nullptr, n, 0);

    // 2) z = Phi_inv @ filtered (keys [0,n); bf16 in/out)
    pull_spmm_bf16<<<row_blocks, 256, 0, stream>>>(
        recs, start, counts, filt_b, z_b, nullptr, n, 0);

    // 3) out = relu(Phi @ (theta .* z))  (keys [n,2n); theta pre-folded; f32 out)
    pull_spmm_bf16<<<row_blocks, 256, 0, stream>>>(
        recs, start + n, counts + n, z_b, nullptr, out, n, 1);
}

// Round 15
// 272.416 us; speedup vs baseline: 1.3209x; 1.0388x over previous
//
#include <hip/hip_runtime.h>

#define CH 128          // C_IN == C_OUT == 128
#define SUMS_BLOCK 512
#define CHUNK_E 4096    // records per chunk = private 32 KB recsTmp window
#define RPT 16          // records per thread in passA (CHUNK_E / 256)
#define BUCKET_BITS 10  // 1024 keys per bucket
#define BKEYS (1 << BUCKET_BITS)
#define NBMAX 512       // max buckets (LDS arrays padded to this)
#define STAG_CAP 18432  // passB LDS out-buffer capacity

__device__ inline ushort f2bf(float f) {          // RNE f32 -> bf16
    unsigned b = __float_as_uint(f);
    return (ushort)((b + 0x7FFF + ((b >> 16) & 1)) >> 16);
}
__device__ inline float bf2f(ushort u) {
    return __uint_as_float((unsigned)u << 16);
}

// ---------- W -> bf16 conversion ----------
__global__ void conv_w_kernel(const float* __restrict__ W,
                              ushort* __restrict__ Wb) {
    int i = blockIdx.x * blockDim.x + threadIdx.x;
    if (i < CH * CH) Wb[i] = f2bf(W[i]);
}

// ---------- pass A v3: single-read, register-held chunk sort --------------
// Triple key space: Phi_inv i -> idxA[i]; Phi -> n+idxB[e]; F -> 2n+idxC[e].
// Thread t owns records [base+t*RPT, base+t*RPT+RPT): loads them ONCE
// (vectorized int4/float4 in the single-matrix fast path), holds packed
// records in registers across the scan, then scatters from registers.
// recsTmp record (8 B): x = c | (key&1023)<<17  (c < 2^17), y = f32 val bits.
__global__ __launch_bounds__(256) void passA_sort(const int* __restrict__ idxA,
                                                  const float* __restrict__ valA,
                                                  const int* __restrict__ idxB,
                                                  const float* __restrict__ valB,
                                                  const int* __restrict__ idxC,
                                                  const float* __restrict__ valC,
                                                  const float* __restrict__ theta,
                                                  int nnz, int n, int nb,
                                                  int* __restrict__ locA,
                                                  int2* __restrict__ recsTmp) {
    __shared__ int hist[NBMAX];
    __shared__ int sc[NBMAX];
    __shared__ int cur[NBMAX];
    int t = threadIdx.x;
    hist[t] = 0; hist[t + 256] = 0;
    __syncthreads();

    int base = blockIdx.x * CHUNK_E;
    int end = min(base + CHUNK_E, 3 * nnz);
    int csize = end - base;
    int rbeg = base + t * RPT;

    int px[RPT];    // packed x (c | keylow<<17)
    int pv[RPT];    // value bits (f32)
    short pb[RPT];  // bucket id

    // ---- phase 1: single load pass, histogram, keep records in registers --
    int nvalid = 0;
    if (rbeg + RPT <= nnz) {
        // fast path: all records in Phi_inv
        #pragma unroll
        for (int r4 = 0; r4 < RPT / 4; ++r4) {
            int4 k4 = *reinterpret_cast<const int4*>(&idxA[rbeg + r4 * 4]);
            int4 c4 = *reinterpret_cast<const int4*>(&idxA[nnz + rbeg + r4 * 4]);
            float4 v4 = *reinterpret_cast<const float4*>(&valA[rbeg + r4 * 4]);
            int kk[4] = {k4.x, k4.y, k4.z, k4.w};
            int cc[4] = {c4.x, c4.y, c4.z, c4.w};
            float vv[4] = {v4.x, v4.y, v4.z, v4.w};
            #pragma unroll
            for (int u = 0; u < 4; ++u) {
                int r = r4 * 4 + u;
                px[r] = cc[u] | ((kk[u] & (BKEYS - 1)) << 17);
                pv[r] = __float_as_int(vv[u]);
                pb[r] = (short)(kk[u] >> BUCKET_BITS);
                atomicAdd(&hist[pb[r]], 1);
            }
        }
        nvalid = RPT;
    } else if (rbeg >= nnz && rbeg + RPT <= 2 * nnz) {
        // fast path: all records in Phi (theta-folded)
        int e0 = rbeg - nnz;
        #pragma unroll
        for (int r4 = 0; r4 < RPT / 4; ++r4) {
            int4 k4 = *reinterpret_cast<const int4*>(&idxB[e0 + r4 * 4]);
            int4 c4 = *reinterpret_cast<const int4*>(&idxB[nnz + e0 + r4 * 4]);
            float4 v4 = *reinterpret_cast<const float4*>(&valB[e0 + r4 * 4]);
            int kk[4] = {k4.x, k4.y, k4.z, k4.w};
            int cc[4] = {c4.x, c4.y, c4.z, c4.w};
            float vv[4] = {v4.x, v4.y, v4.z, v4.w};
            #pragma unroll
            for (int u = 0; u < 4; ++u) {
                int r = r4 * 4 + u;
                int key = n + kk[u];
                px[r] = cc[u] | ((key & (BKEYS - 1)) << 17);
                pv[r] = __float_as_int(vv[u] * theta[cc[u]]);
                pb[r] = (short)(key >> BUCKET_BITS);
                atomicAdd(&hist[pb[r]], 1);
            }
        }
        nvalid = RPT;
    } else if (rbeg >= 2 * nnz && rbeg + RPT <= 3 * nnz) {
        // fast path: all records in F
        int e0 = rbeg - 2 * nnz;
        #pragma unroll
        for (int r4 = 0; r4 < RPT / 4; ++r4) {
            int4 k4 = *reinterpret_cast<const int4*>(&idxC[e0 + r4 * 4]);
            int4 c4 = *reinterpret_cast<const int4*>(&idxC[nnz + e0 + r4 * 4]);
            float4 v4 = *reinterpret_cast<const float4*>(&valC[e0 + r4 * 4]);
            int kk[4] = {k4.x, k4.y, k4.z, k4.w};
            int cc[4] = {c4.x, c4.y, c4.z, c4.w};
            float vv[4] = {v4.x, v4.y, v4.z, v4.w};
            #pragma unroll
            for (int u = 0; u < 4; ++u) {
                int r = r4 * 4 + u;
                int key = 2 * n + kk[u];
                px[r] = cc[u] | ((key & (BKEYS - 1)) << 17);
                pv[r] = __float_as_int(vv[u]);
                pb[r] = (short)(key >> BUCKET_BITS);
                atomicAdd(&hist[pb[r]], 1);
            }
        }
        nvalid = RPT;
    } else {
        // slow path (matrix-boundary or tail threads): scalar per record
        #pragma unroll
        for (int r = 0; r < RPT; ++r) {
            int i = rbeg + r;
            if (i >= end) break;
            int key, c;
            float v;
            if (i < nnz) {
                key = idxA[i];
                c = idxA[nnz + i];
                v = valA[i];
            } else if (i < 2 * nnz) {
                int e = i - nnz;
                key = n + idxB[e];
                c = idxB[nnz + e];
                v = valB[e] * theta[c];
            } else {
                int e = i - 2 * nnz;
                key = 2 * n + idxC[e];
                c = idxC[nnz + e];
                v = valC[e];
            }
            px[r] = c | ((key & (BKEYS - 1)) << 17);
            pv[r] = __float_as_int(v);
            pb[r] = (short)(key >> BUCKET_BITS);
            atomicAdd(&hist[pb[r]], 1);
            ++nvalid;
        }
    }
    __syncthreads();

    // ---- phase 2: inclusive scan over 512 slots (2/thread) ----
    sc[t] = hist[t]; sc[t + 256] = hist[t + 256];
    __syncthreads();
    for (int off = 1; off < NBMAX; off <<= 1) {
        int a = (t >= off) ? sc[t - off] : 0;
        int b2 = (t + 256 >= off) ? sc[t + 256 - off] : 0;
        __syncthreads();
        sc[t] += a; sc[t + 256] += b2;
        __syncthreads();
    }
    cur[t] = sc[t] - hist[t];
    cur[t + 256] = sc[t + 256] - hist[t + 256];
    __syncthreads();

    // metadata: contiguous chunk-major write (local exclusive starts + sentinel)
    for (int b = t; b <= nb; b += 256)
        locA[(size_t)blockIdx.x * (nb + 1) + b] = (b < nb) ? (sc[b] - hist[b]) : csize;

    // ---- phase 3: scatter from registers into private 32 KB window ----
    #pragma unroll
    for (int r = 0; r < RPT; ++r) {
        if (r < nvalid) {
            int pos = atomicAdd(&cur[pb[r]], 1);
            recsTmp[(size_t)base + pos] = make_int2(px[r], pv[r]);
        }
    }
}

// ---------- bucket totals: tot[b] = sum over chunks of segment length -----
__global__ __launch_bounds__(256) void bucket_totals(const int* __restrict__ locA,
                                                     int nchA, int nb,
                                                     int* __restrict__ tot) {
    __shared__ int red[256];
    int b = blockIdx.x;
    int t = threadIdx.x;
    int s = 0;
    for (int ch = t; ch < nchA; ch += 256) {
        const int* lc = &locA[(size_t)ch * (nb + 1)];
        s += lc[b + 1] - lc[b];
    }
    red[t] = s;
    __syncthreads();
    for (int off = 128; off > 0; off >>= 1) {
        if (t < off) red[t] += red[t + off];
        __syncthreads();
    }
    if (t == 0) tot[b] = red[0];
}

// exclusive scan in place over tot[0..len)
__global__ void scan_sums_kernel(int* __restrict__ chunk_sums, int nchunks) {
    __shared__ int tmp[SUMS_BLOCK];
    __shared__ int carry_s;
    int tid = threadIdx.x;
    if (tid == 0) carry_s = 0;
    __syncthreads();
    for (int base = 0; base < nchunks; base += SUMS_BLOCK) {
        int i = base + tid;
        int v = (i < nchunks) ? chunk_sums[i] : 0;
        tmp[tid] = v;
        __syncthreads();
        for (int off = 1; off < SUMS_BLOCK; off <<= 1) {
            int y = (tid >= off) ? tmp[tid - off] : 0;
            __syncthreads();
            tmp[tid] += y;
            __syncthreads();
        }
        int c = carry_s;
        if (i < nchunks) chunk_sums[i] = tmp[tid] - v + c;   // exclusive
        int total = tmp[SUMS_BLOCK - 1];
        __syncthreads();
        if (tid == 0) carry_s = c + total;
        __syncthreads();
    }
}

// ---------- pass B: key-sort into LDS out-buffer, linear flush ------------
// rec = (c << 15) | (bf16(v) & 0x7FFF)  -- all values positive.
__global__ __launch_bounds__(1024) void passB_kernel(const int2* __restrict__ recsTmp,
                                                     const int* __restrict__ locA,
                                                     const int* __restrict__ bsArr,
                                                     int nchA, int nb, int n3,
                                                     int* __restrict__ start_g,
                                                     int* __restrict__ counts_g,
                                                     unsigned* __restrict__ recs) {
    __shared__ int hist[BKEYS];          // 4 KB
    __shared__ int scan[BKEYS];          // 4 KB
    __shared__ unsigned outb[STAG_CAP];  // 72 KB
    int b = blockIdx.x;
    int t = threadIdx.x;
    int wave = t >> 6, lane = t & 63;
    int grp = lane >> 4, gl = lane & 15;    // 4 chunk-groups per wave
    int bs = bsArr[b];
    hist[t] = 0;
    __syncthreads();

    // phase 1: key histogram (64 chunks in flight across the block)
    for (int ch = wave * 4 + grp; ch < nchA; ch += 64) {
        const int* lc = &locA[(size_t)ch * (nb + 1)];
        int ls = lc[b], le = lc[b + 1];
        size_t cb = (size_t)ch * CHUNK_E;
        for (int k = ls + gl; k < le; k += 16)
            atomicAdd(&hist[(recsTmp[cb + k].x >> 17) & (BKEYS - 1)], 1);
    }
    __syncthreads();

    // phase 2: scan 1024 keys
    int v = hist[t];
    scan[t] = v;
    __syncthreads();
    for (int off = 1; off < BKEYS; off <<= 1) {
        int y = (t >= off) ? scan[t - off] : 0;
        __syncthreads();
        scan[t] += y;
        __syncthreads();
    }
    int excl = scan[t] - v;
    int key = (b << BUCKET_BITS) + t;
    if (key < n3) {
        start_g[key] = bs + excl;
        counts_g[key] = v;
    }
    int totalB = scan[BKEYS - 1];
    hist[t] = excl;                      // reuse as cursor
    __syncthreads();

    if (totalB <= STAG_CAP) {
        // phase 3: re-read segments, pack, scatter into LDS out-buffer
        for (int ch = wave * 4 + grp; ch < nchA; ch += 64) {
            const int* lc = &locA[(size_t)ch * (nb + 1)];
            int ls = lc[b], le = lc[b + 1];
            size_t cb = (size_t)ch * CHUNK_E;
            for (int k = ls + gl; k < le; k += 16) {
                int2 r = recsTmp[cb + k];
                int kk = (r.x >> 17) & (BKEYS - 1);
                int pos = atomicAdd(&hist[kk], 1);
                unsigned c = (unsigned)(r.x & 0x1FFFF);
                unsigned bv = (unsigned)f2bf(__int_as_float(r.y)) & 0x7FFFu;
                outb[pos] = (c << 15) | bv;
            }
        }
        __syncthreads();
        // phase 4: linear coalesced flush
        for (int k = t; k < totalB; k += 1024)
            recs[(size_t)bs + k] = outb[k];
    } else {
        // fallback (statistically unreachable): direct global scatter
        for (int ch = wave * 4 + grp; ch < nchA; ch += 64) {
            const int* lc = &locA[(size_t)ch * (nb + 1)];
            int ls = lc[b], le = lc[b + 1];
            size_t cb = (size_t)ch * CHUNK_E;
            for (int k = ls + gl; k < le; k += 16) {
                int2 r = recsTmp[cb + k];
                int kk = (r.x >> 17) & (BKEYS - 1);
                int pos = atomicAdd(&hist[kk], 1);
                unsigned c = (unsigned)(r.x & 0x1FFFF);
                unsigned bv = (unsigned)f2bf(__int_as_float(r.y)) & 0x7FFFu;
                recs[(size_t)bs + pos] = (c << 15) | bv;
            }
        }
    }
}

// ---------- Pull SpMM (bf16 dense operand, 4 B records) ------------------
__global__ __launch_bounds__(256) void pull_spmm_bf16(
        const unsigned* __restrict__ recs,
        const int* __restrict__ start,
        const int* __restrict__ counts,
        const ushort* __restrict__ dense,   // bf16 rows of 128
        ushort* __restrict__ outb,          // bf16 out (or null)
        float* __restrict__ outf,           // f32 out (or null)
        int n, int do_relu) {
    int wave = threadIdx.x >> 6;
    int lane = threadIdx.x & 63;
    int row = blockIdx.x * 4 + wave;
    if (row >= n) return;
    int s = start[row];
    int cnt = counts[row];
    const ushort2* dp = reinterpret_cast<const ushort2*>(dense);
    float ax = 0.0f, ay = 0.0f;
    int j = 0;
    for (; j + 4 <= cnt; j += 4) {
        unsigned r0 = recs[s + j + 0];
        unsigned r1 = recs[s + j + 1];
        unsigned r2 = recs[s + j + 2];
        unsigned r3 = recs[s + j + 3];
        ushort2 d0 = dp[(size_t)(r0 >> 15) * 64 + lane];
        ushort2 d1 = dp[(size_t)(r1 >> 15) * 64 + lane];
        ushort2 d2 = dp[(size_t)(r2 >> 15) * 64 + lane];
        ushort2 d3 = dp[(size_t)(r3 >> 15) * 64 + lane];
        float v0 = __uint_as_float((r0 & 0x7FFFu) << 16);
        float v1 = __uint_as_float((r1 & 0x7FFFu) << 16);
        float v2 = __uint_as_float((r2 & 0x7FFFu) << 16);
        float v3 = __uint_as_float((r3 & 0x7FFFu) << 16);
        ax = fmaf(v0, bf2f(d0.x), ax); ay = fmaf(v0, bf2f(d0.y), ay);
        ax = fmaf(v1, bf2f(d1.x), ax); ay = fmaf(v1, bf2f(d1.y), ay);
        ax = fmaf(v2, bf2f(d2.x), ax); ay = fmaf(v2, bf2f(d2.y), ay);
        ax = fmaf(v3, bf2f(d3.x), ax); ay = fmaf(v3, bf2f(d3.y), ay);
    }
    for (; j < cnt; ++j) {
        unsigned r0 = recs[s + j];
        ushort2 d0 = dp[(size_t)(r0 >> 15) * 64 + lane];
        float v0 = __uint_as_float((r0 & 0x7FFFu) << 16);
        ax = fmaf(v0, bf2f(d0.x), ax); ay = fmaf(v0, bf2f(d0.y), ay);
    }
    if (do_relu) { ax = fmaxf(ax, 0.0f); ay = fmaxf(ay, 0.0f); }
    if (outb) {
        ushort2 o = {f2bf(ax), f2bf(ay)};
        reinterpret_cast<ushort2*>(outb)[(size_t)row * 64 + lane] = o;
    } else {
        float2 o = {ax, ay};
        *reinterpret_cast<float2*>(&outf[(size_t)row * CH + lane * 2]) = o;
    }
}

// ---------- host-side orchestration ----------

extern "C" void kernel_launch(void* const* d_in, const int* in_sizes, int n_in,
                              void* d_out, int out_size, void* d_ws, size_t ws_size,
                              hipStream_t stream) {
    const int*   phi_idx  = (const int*)d_in[0];
    const float* phi_val  = (const float*)d_in[1];
    const int*   phii_idx = (const int*)d_in[2];
    const float* phii_val = (const float*)d_in[3];
    const int*   f_idx    = (const int*)d_in[4];
    const float* f_val    = (const float*)d_in[5];
    const float* W        = (const float*)d_in[6];
    const float* theta    = (const float*)d_in[7];

    const int nnz = in_sizes[1];            // 1,600,000
    const int n   = in_sizes[7];            // 100,000
    const int n3  = 3 * n;                  // triple key space
    const int total = 3 * nnz;              // 4.8M records

    const int nb   = (n3 + BKEYS - 1) >> BUCKET_BITS;               // 293 (<=511)
    const int nchA = (total + CHUNK_E - 1) / CHUNK_E;               // 1172

    float* out = (float*)d_out;

    // workspace (~75 MB). The 51.2 MB "dense region" holds recsTmp (38.4 MB)
    // during the build; after passB it is reused as filtered_bf16 [0,25.6)
    // and z_bf16 [25.6,51.2).
    char* ws = (char*)d_ws;
    char*  dense_region = ws;
    int2*  recsTmp  = (int2*)dense_region;                 // 38.4 MB (build only)
    ushort* filt_b  = (ushort*)dense_region;               // 25.6 MB
    ushort* z_b     = (ushort*)(dense_region + (size_t)n * CH * sizeof(ushort));
    ws += (size_t)n * CH * sizeof(float);                  // 51.2 MB region
    unsigned* recs  = (unsigned*)ws;        ws += (size_t)total * sizeof(unsigned);
    int* counts     = (int*)ws;             ws += (size_t)n3 * sizeof(int);
    int* start      = (int*)ws;             ws += (size_t)n3 * sizeof(int);
    int* locA       = (int*)ws;             ws += (size_t)nchA * (nb + 1) * sizeof(int);
    int* tot        = (int*)ws;             ws += 4096;
    ushort* w_b     = (ushort*)ws;          ws += CH * CH * sizeof(ushort);

    const int row_blocks = (n + 3) / 4;

    // --- W -> bf16 (independent; overlaps build) ---
    conv_w_kernel<<<(CH * CH + 255) / 256, 256, 0, stream>>>(W, w_b);

    // --- radix CSR build: all three sparse matrices in one key space ---
    passA_sort<<<nchA, 256, 0, stream>>>(phii_idx, phii_val, phi_idx, phi_val,
                                         f_idx, f_val, theta,
                                         nnz, n, nb, locA, recsTmp);
    bucket_totals<<<nb, 256, 0, stream>>>(locA, nchA, nb, tot);
    scan_sums_kernel<<<1, SUMS_BLOCK, 0, stream>>>(tot, nb);
    passB_kernel<<<nb, 1024, 0, stream>>>(recsTmp, locA, tot, nchA, nb, n3,
                                          start, counts, recs);

    // 1) filtered = F @ W       (keys [2n,3n); W bf16 L1-resident; bf16 out)
    pull_spmm_bf16<<<row_blocks, 256, 0, stream>>>(
        recs, start + 2 * n, counts + 2 * n, w_b, filt_b, nullptr, n, 0);

    // 2) z = Phi_inv @ filtered (keys [0,n); bf16 in/out)
    pull_spmm_bf16<<<row_blocks, 256, 0, stream>>>(
        recs, start, counts, filt_b, z_b, nullptr, n, 0);

    // 3) out = relu(Phi @ (theta .* z))  (keys [n,2n); theta pre-folded; f32 out)
    pull_spmm_bf16<<<row_blocks, 256, 0, stream>>>(
        recs, start + n, counts + n, z_b, nullptr, out, n, 1);
}

// Round 16
// 236.587 us; speedup vs baseline: 1.5210x; 1.1514x over previous
//
#include <hip/hip_runtime.h>

#define CH 128          // C_IN == C_OUT == 128
#define SUMS_BLOCK 512
#define CHUNK_E 4096    // records per chunk = private 32 KB recsTmp window
#define RPT 16          // records per thread in passA (CHUNK_E / 256)
#define BUCKET_BITS 10  // 1024 keys per bucket
#define BKEYS (1 << BUCKET_BITS)
#define NBMAX 512       // max buckets (LDS arrays padded to this)
#define STAG_CAP 18432  // passB LDS out-buffer capacity

__device__ inline ushort f2bf(float f) {          // RNE f32 -> bf16
    unsigned b = __float_as_uint(f);
    return (ushort)((b + 0x7FFF + ((b >> 16) & 1)) >> 16);
}
__device__ inline float bf2f(ushort u) {
    return __uint_as_float((unsigned)u << 16);
}

// ---------- W -> bf16 conversion ----------
__global__ void conv_w_kernel(const float* __restrict__ W,
                              ushort* __restrict__ Wb) {
    int i = blockIdx.x * blockDim.x + threadIdx.x;
    if (i < CH * CH) Wb[i] = f2bf(W[i]);
}

// ---------- pass A v3: single-read, register-held chunk sort --------------
__global__ __launch_bounds__(256) void passA_sort(const int* __restrict__ idxA,
                                                  const float* __restrict__ valA,
                                                  const int* __restrict__ idxB,
                                                  const float* __restrict__ valB,
                                                  const int* __restrict__ idxC,
                                                  const float* __restrict__ valC,
                                                  const float* __restrict__ theta,
                                                  int nnz, int n, int nb,
                                                  int* __restrict__ locA,
                                                  int2* __restrict__ recsTmp) {
    __shared__ int hist[NBMAX];
    __shared__ int sc[NBMAX];
    __shared__ int cur[NBMAX];
    int t = threadIdx.x;
    hist[t] = 0; hist[t + 256] = 0;
    __syncthreads();

    int base = blockIdx.x * CHUNK_E;
    int end = min(base + CHUNK_E, 3 * nnz);
    int csize = end - base;
    int rbeg = base + t * RPT;

    int px[RPT];    // packed x (c | keylow<<17)
    int pv[RPT];    // value bits (f32)
    short pb[RPT];  // bucket id

    int nvalid = 0;
    if (rbeg + RPT <= nnz) {
        #pragma unroll
        for (int r4 = 0; r4 < RPT / 4; ++r4) {
            int4 k4 = *reinterpret_cast<const int4*>(&idxA[rbeg + r4 * 4]);
            int4 c4 = *reinterpret_cast<const int4*>(&idxA[nnz + rbeg + r4 * 4]);
            float4 v4 = *reinterpret_cast<const float4*>(&valA[rbeg + r4 * 4]);
            int kk[4] = {k4.x, k4.y, k4.z, k4.w};
            int cc[4] = {c4.x, c4.y, c4.z, c4.w};
            float vv[4] = {v4.x, v4.y, v4.z, v4.w};
            #pragma unroll
            for (int u = 0; u < 4; ++u) {
                int r = r4 * 4 + u;
                px[r] = cc[u] | ((kk[u] & (BKEYS - 1)) << 17);
                pv[r] = __float_as_int(vv[u]);
                pb[r] = (short)(kk[u] >> BUCKET_BITS);
                atomicAdd(&hist[pb[r]], 1);
            }
        }
        nvalid = RPT;
    } else if (rbeg >= nnz && rbeg + RPT <= 2 * nnz) {
        int e0 = rbeg - nnz;
        #pragma unroll
        for (int r4 = 0; r4 < RPT / 4; ++r4) {
            int4 k4 = *reinterpret_cast<const int4*>(&idxB[e0 + r4 * 4]);
            int4 c4 = *reinterpret_cast<const int4*>(&idxB[nnz + e0 + r4 * 4]);
            float4 v4 = *reinterpret_cast<const float4*>(&valB[e0 + r4 * 4]);
            int kk[4] = {k4.x, k4.y, k4.z, k4.w};
            int cc[4] = {c4.x, c4.y, c4.z, c4.w};
            float vv[4] = {v4.x, v4.y, v4.z, v4.w};
            #pragma unroll
            for (int u = 0; u < 4; ++u) {
                int r = r4 * 4 + u;
                int key = n + kk[u];
                px[r] = cc[u] | ((key & (BKEYS - 1)) << 17);
                pv[r] = __float_as_int(vv[u] * theta[cc[u]]);
                pb[r] = (short)(key >> BUCKET_BITS);
                atomicAdd(&hist[pb[r]], 1);
            }
        }
        nvalid = RPT;
    } else if (rbeg >= 2 * nnz && rbeg + RPT <= 3 * nnz) {
        int e0 = rbeg - 2 * nnz;
        #pragma unroll
        for (int r4 = 0; r4 < RPT / 4; ++r4) {
            int4 k4 = *reinterpret_cast<const int4*>(&idxC[e0 + r4 * 4]);
            int4 c4 = *reinterpret_cast<const int4*>(&idxC[nnz + e0 + r4 * 4]);
            float4 v4 = *reinterpret_cast<const float4*>(&valC[e0 + r4 * 4]);
            int kk[4] = {k4.x, k4.y, k4.z, k4.w};
            int cc[4] = {c4.x, c4.y, c4.z, c4.w};
            float vv[4] = {v4.x, v4.y, v4.z, v4.w};
            #pragma unroll
            for (int u = 0; u < 4; ++u) {
                int r = r4 * 4 + u;
                int key = 2 * n + kk[u];
                px[r] = cc[u] | ((key & (BKEYS - 1)) << 17);
                pv[r] = __float_as_int(vv[u]);
                pb[r] = (short)(key >> BUCKET_BITS);
                atomicAdd(&hist[pb[r]], 1);
            }
        }
        nvalid = RPT;
    } else {
        #pragma unroll
        for (int r = 0; r < RPT; ++r) {
            int i = rbeg + r;
            if (i >= end) break;
            int key, c;
            float v;
            if (i < nnz) {
                key = idxA[i];
                c = idxA[nnz + i];
                v = valA[i];
            } else if (i < 2 * nnz) {
                int e = i - nnz;
                key = n + idxB[e];
                c = idxB[nnz + e];
                v = valB[e] * theta[c];
            } else {
                int e = i - 2 * nnz;
                key = 2 * n + idxC[e];
                c = idxC[nnz + e];
                v = valC[e];
            }
            px[r] = c | ((key & (BKEYS - 1)) << 17);
            pv[r] = __float_as_int(v);
            pb[r] = (short)(key >> BUCKET_BITS);
            atomicAdd(&hist[pb[r]], 1);
            ++nvalid;
        }
    }
    __syncthreads();

    sc[t] = hist[t]; sc[t + 256] = hist[t + 256];
    __syncthreads();
    for (int off = 1; off < NBMAX; off <<= 1) {
        int a = (t >= off) ? sc[t - off] : 0;
        int b2 = (t + 256 >= off) ? sc[t + 256 - off] : 0;
        __syncthreads();
        sc[t] += a; sc[t + 256] += b2;
        __syncthreads();
    }
    cur[t] = sc[t] - hist[t];
    cur[t + 256] = sc[t + 256] - hist[t + 256];
    __syncthreads();

    for (int b = t; b <= nb; b += 256)
        locA[(size_t)blockIdx.x * (nb + 1) + b] = (b < nb) ? (sc[b] - hist[b]) : csize;

    #pragma unroll
    for (int r = 0; r < RPT; ++r) {
        if (r < nvalid) {
            int pos = atomicAdd(&cur[pb[r]], 1);
            recsTmp[(size_t)base + pos] = make_int2(px[r], pv[r]);
        }
    }
}

// ---------- bucket totals ----------
__global__ __launch_bounds__(256) void bucket_totals(const int* __restrict__ locA,
                                                     int nchA, int nb,
                                                     int* __restrict__ tot) {
    __shared__ int red[256];
    int b = blockIdx.x;
    int t = threadIdx.x;
    int s = 0;
    for (int ch = t; ch < nchA; ch += 256) {
        const int* lc = &locA[(size_t)ch * (nb + 1)];
        s += lc[b + 1] - lc[b];
    }
    red[t] = s;
    __syncthreads();
    for (int off = 128; off > 0; off >>= 1) {
        if (t < off) red[t] += red[t + off];
        __syncthreads();
    }
    if (t == 0) tot[b] = red[0];
}

__global__ void scan_sums_kernel(int* __restrict__ chunk_sums, int nchunks) {
    __shared__ int tmp[SUMS_BLOCK];
    __shared__ int carry_s;
    int tid = threadIdx.x;
    if (tid == 0) carry_s = 0;
    __syncthreads();
    for (int base = 0; base < nchunks; base += SUMS_BLOCK) {
        int i = base + tid;
        int v = (i < nchunks) ? chunk_sums[i] : 0;
        tmp[tid] = v;
        __syncthreads();
        for (int off = 1; off < SUMS_BLOCK; off <<= 1) {
            int y = (tid >= off) ? tmp[tid - off] : 0;
            __syncthreads();
            tmp[tid] += y;
            __syncthreads();
        }
        int c = carry_s;
        if (i < nchunks) chunk_sums[i] = tmp[tid] - v + c;   // exclusive
        int total = tmp[SUMS_BLOCK - 1];
        __syncthreads();
        if (tid == 0) carry_s = c + total;
        __syncthreads();
    }
}

// ---------- pass B: key-sort into LDS out-buffer, linear flush ------------
__global__ __launch_bounds__(1024) void passB_kernel(const int2* __restrict__ recsTmp,
                                                     const int* __restrict__ locA,
                                                     const int* __restrict__ bsArr,
                                                     int nchA, int nb, int n3,
                                                     int* __restrict__ start_g,
                                                     int* __restrict__ counts_g,
                                                     unsigned* __restrict__ recs) {
    __shared__ int hist[BKEYS];          // 4 KB
    __shared__ int scan[BKEYS];          // 4 KB
    __shared__ unsigned outb[STAG_CAP];  // 72 KB
    int b = blockIdx.x;
    int t = threadIdx.x;
    int wave = t >> 6, lane = t & 63;
    int grp = lane >> 4, gl = lane & 15;
    int bs = bsArr[b];
    hist[t] = 0;
    __syncthreads();

    for (int ch = wave * 4 + grp; ch < nchA; ch += 64) {
        const int* lc = &locA[(size_t)ch * (nb + 1)];
        int ls = lc[b], le = lc[b + 1];
        size_t cb = (size_t)ch * CHUNK_E;
        for (int k = ls + gl; k < le; k += 16)
            atomicAdd(&hist[(recsTmp[cb + k].x >> 17) & (BKEYS - 1)], 1);
    }
    __syncthreads();

    int v = hist[t];
    scan[t] = v;
    __syncthreads();
    for (int off = 1; off < BKEYS; off <<= 1) {
        int y = (t >= off) ? scan[t - off] : 0;
        __syncthreads();
        scan[t] += y;
        __syncthreads();
    }
    int excl = scan[t] - v;
    int key = (b << BUCKET_BITS) + t;
    if (key < n3) {
        start_g[key] = bs + excl;
        counts_g[key] = v;
    }
    int totalB = scan[BKEYS - 1];
    hist[t] = excl;                      // reuse as cursor
    __syncthreads();

    if (totalB <= STAG_CAP) {
        for (int ch = wave * 4 + grp; ch < nchA; ch += 64) {
            const int* lc = &locA[(size_t)ch * (nb + 1)];
            int ls = lc[b], le = lc[b + 1];
            size_t cb = (size_t)ch * CHUNK_E;
            for (int k = ls + gl; k < le; k += 16) {
                int2 r = recsTmp[cb + k];
                int kk = (r.x >> 17) & (BKEYS - 1);
                int pos = atomicAdd(&hist[kk], 1);
                unsigned c = (unsigned)(r.x & 0x1FFFF);
                unsigned bv = (unsigned)f2bf(__int_as_float(r.y)) & 0x7FFFu;
                outb[pos] = (c << 15) | bv;
            }
        }
        __syncthreads();
        for (int k = t; k < totalB; k += 1024)
            recs[(size_t)bs + k] = outb[k];
    } else {
        for (int ch = wave * 4 + grp; ch < nchA; ch += 64) {
            const int* lc = &locA[(size_t)ch * (nb + 1)];
            int ls = lc[b], le = lc[b + 1];
            size_t cb = (size_t)ch * CHUNK_E;
            for (int k = ls + gl; k < le; k += 16) {
                int2 r = recsTmp[cb + k];
                int kk = (r.x >> 17) & (BKEYS - 1);
                int pos = atomicAdd(&hist[kk], 1);
                unsigned c = (unsigned)(r.x & 0x1FFFF);
                unsigned bv = (unsigned)f2bf(__int_as_float(r.y)) & 0x7FFFu;
                recs[(size_t)bs + pos] = (c << 15) | bv;
            }
        }
    }
}

// ---------- Pull SpMM v2: 32 lanes/row, cooperative rec prefetch + shfl ---
// Each 32-lane group owns one row (2 rows/wave, 8 rows/block). Up to 32
// records are loaded by one vector load, then broadcast via __shfl(w=32):
// the serial rec-load latency chain collapses to one VMEM op per 32 recs.
__global__ __launch_bounds__(256) void pull_spmm_bf16(
        const unsigned* __restrict__ recs,
        const int* __restrict__ start,
        const int* __restrict__ counts,
        const ushort* __restrict__ dense,   // bf16 rows of 128
        ushort* __restrict__ outb,          // bf16 out (or null)
        float* __restrict__ outf,           // f32 out (or null)
        int n, int do_relu) {
    int grp32 = threadIdx.x >> 5;           // 8 row-groups per block
    int lane = threadIdx.x & 31;
    int row = blockIdx.x * 8 + grp32;
    if (row >= n) return;
    int s = start[row];
    int cnt = counts[row];
    const ushort4* dp = reinterpret_cast<const ushort4*>(dense);  // 32 per row
    float a0 = 0.0f, a1 = 0.0f, a2 = 0.0f, a3 = 0.0f;

    for (int jb = 0; jb < cnt; jb += 32) {
        int nbatch = min(32, cnt - jb);
        unsigned myrec = (lane < nbatch) ? recs[s + jb + lane] : 0u;
        int j = 0;
        for (; j + 4 <= nbatch; j += 4) {
            unsigned r0 = __shfl(myrec, j + 0, 32);
            unsigned r1 = __shfl(myrec, j + 1, 32);
            unsigned r2 = __shfl(myrec, j + 2, 32);
            unsigned r3 = __shfl(myrec, j + 3, 32);
            ushort4 d0 = dp[(size_t)(r0 >> 15) * 32 + lane];
            ushort4 d1 = dp[(size_t)(r1 >> 15) * 32 + lane];
            ushort4 d2 = dp[(size_t)(r2 >> 15) * 32 + lane];
            ushort4 d3 = dp[(size_t)(r3 >> 15) * 32 + lane];
            float v0 = __uint_as_float((r0 & 0x7FFFu) << 16);
            float v1 = __uint_as_float((r1 & 0x7FFFu) << 16);
            float v2 = __uint_as_float((r2 & 0x7FFFu) << 16);
            float v3 = __uint_as_float((r3 & 0x7FFFu) << 16);
            a0 = fmaf(v0, bf2f(d0.x), a0); a1 = fmaf(v0, bf2f(d0.y), a1);
            a2 = fmaf(v0, bf2f(d0.z), a2); a3 = fmaf(v0, bf2f(d0.w), a3);
            a0 = fmaf(v1, bf2f(d1.x), a0); a1 = fmaf(v1, bf2f(d1.y), a1);
            a2 = fmaf(v1, bf2f(d1.z), a2); a3 = fmaf(v1, bf2f(d1.w), a3);
            a0 = fmaf(v2, bf2f(d2.x), a0); a1 = fmaf(v2, bf2f(d2.y), a1);
            a2 = fmaf(v2, bf2f(d2.z), a2); a3 = fmaf(v2, bf2f(d2.w), a3);
            a0 = fmaf(v3, bf2f(d3.x), a0); a1 = fmaf(v3, bf2f(d3.y), a1);
            a2 = fmaf(v3, bf2f(d3.z), a2); a3 = fmaf(v3, bf2f(d3.w), a3);
        }
        for (; j < nbatch; ++j) {
            unsigned r0 = __shfl(myrec, j, 32);
            ushort4 d0 = dp[(size_t)(r0 >> 15) * 32 + lane];
            float v0 = __uint_as_float((r0 & 0x7FFFu) << 16);
            a0 = fmaf(v0, bf2f(d0.x), a0); a1 = fmaf(v0, bf2f(d0.y), a1);
            a2 = fmaf(v0, bf2f(d0.z), a2); a3 = fmaf(v0, bf2f(d0.w), a3);
        }
    }
    if (do_relu) {
        a0 = fmaxf(a0, 0.0f); a1 = fmaxf(a1, 0.0f);
        a2 = fmaxf(a2, 0.0f); a3 = fmaxf(a3, 0.0f);
    }
    if (outb) {
        ushort4 o = {f2bf(a0), f2bf(a1), f2bf(a2), f2bf(a3)};
        reinterpret_cast<ushort4*>(outb)[(size_t)row * 32 + lane] = o;
    } else {
        float4 o = {a0, a1, a2, a3};
        *reinterpret_cast<float4*>(&outf[(size_t)row * CH + lane * 4]) = o;
    }
}

// ---------- host-side orchestration ----------

extern "C" void kernel_launch(void* const* d_in, const int* in_sizes, int n_in,
                              void* d_out, int out_size, void* d_ws, size_t ws_size,
                              hipStream_t stream) {
    const int*   phi_idx  = (const int*)d_in[0];
    const float* phi_val  = (const float*)d_in[1];
    const int*   phii_idx = (const int*)d_in[2];
    const float* phii_val = (const float*)d_in[3];
    const int*   f_idx    = (const int*)d_in[4];
    const float* f_val    = (const float*)d_in[5];
    const float* W        = (const float*)d_in[6];
    const float* theta    = (const float*)d_in[7];

    const int nnz = in_sizes[1];            // 1,600,000
    const int n   = in_sizes[7];            // 100,000
    const int n3  = 3 * n;                  // triple key space
    const int total = 3 * nnz;              // 4.8M records

    const int nb   = (n3 + BKEYS - 1) >> BUCKET_BITS;               // 293 (<=511)
    const int nchA = (total + CHUNK_E - 1) / CHUNK_E;               // 1172

    float* out = (float*)d_out;

    // workspace (~75 MB). The 51.2 MB "dense region" holds recsTmp (38.4 MB)
    // during the build; after passB it is reused as filtered_bf16 [0,25.6)
    // and z_bf16 [25.6,51.2).
    char* ws = (char*)d_ws;
    char*  dense_region = ws;
    int2*  recsTmp  = (int2*)dense_region;                 // 38.4 MB (build only)
    ushort* filt_b  = (ushort*)dense_region;               // 25.6 MB
    ushort* z_b     = (ushort*)(dense_region + (size_t)n * CH * sizeof(ushort));
    ws += (size_t)n * CH * sizeof(float);                  // 51.2 MB region
    unsigned* recs  = (unsigned*)ws;        ws += (size_t)total * sizeof(unsigned);
    int* counts     = (int*)ws;             ws += (size_t)n3 * sizeof(int);
    int* start      = (int*)ws;             ws += (size_t)n3 * sizeof(int);
    int* locA       = (int*)ws;             ws += (size_t)nchA * (nb + 1) * sizeof(int);
    int* tot        = (int*)ws;             ws += 4096;
    ushort* w_b     = (ushort*)ws;          ws += CH * CH * sizeof(ushort);

    const int row_blocks = (n + 7) / 8;     // 8 rows per 256-thread block

    // --- W -> bf16 (independent; overlaps build) ---
    conv_w_kernel<<<(CH * CH + 255) / 256, 256, 0, stream>>>(W, w_b);

    // --- radix CSR build: all three sparse matrices in one key space ---
    passA_sort<<<nchA, 256, 0, stream>>>(phii_idx, phii_val, phi_idx, phi_val,
                                         f_idx, f_val, theta,
                                         nnz, n, nb, locA, recsTmp);
    bucket_totals<<<nb, 256, 0, stream>>>(locA, nchA, nb, tot);
    scan_sums_kernel<<<1, SUMS_BLOCK, 0, stream>>>(tot, nb);
    passB_kernel<<<nb, 1024, 0, stream>>>(recsTmp, locA, tot, nchA, nb, n3,
                                          start, counts, recs);

    // 1) filtered = F @ W       (keys [2n,3n); W bf16 L1-resident; bf16 out)
    pull_spmm_bf16<<<row_blocks, 256, 0, stream>>>(
        recs, start + 2 * n, counts + 2 * n, w_b, filt_b, nullptr, n, 0);

    // 2) z = Phi_inv @ filtered (keys [0,n); bf16 in/out)
    pull_spmm_bf16<<<row_blocks, 256, 0, stream>>>(
        recs, start, counts, filt_b, z_b, nullptr, n, 0);

    // 3) out = relu(Phi @ (theta .* z))  (keys [n,2n); theta pre-folded; f32 out)
    pull_spmm_bf16<<<row_blocks, 256, 0, stream>>>(
        recs, start + n, counts + n, z_b, nullptr, out, n, 1);
}